// Round 4
// baseline (245.222 us; speedup 1.0000x reference)
//
#include <hip/hip_runtime.h>
#include <hip/hip_bf16.h>
#include <stdint.h>

#define KDIM 4096

typedef __attribute__((ext_vector_type(8))) short bf16x8;
typedef __attribute__((ext_vector_type(4))) float f32x4;

__device__ inline unsigned short f2bf_bits(float f) {
  union { __hip_bfloat16 h; unsigned short u; } cv;
  cv.h = __float2bfloat16(f);
  return cv.u;
}

// Fused quant+dequant for both tensors. One 8-lane subgroup = one 32-elem block.
// Palette selection via per-block thresholds (midpoint/6 * block_max);
// ties go to the LOWER palette value (argmin-first semantics).
__global__ void nvfp4_quant_dq2(const float* __restrict__ x, unsigned short* __restrict__ xq,
                                int nsub_x,
                                const float* __restrict__ w, unsigned short* __restrict__ wq,
                                int nsub_total) {
  int gid = blockIdx.x * blockDim.x + threadIdx.x;
  int sub = gid >> 3;
  if (sub >= nsub_total) return;
  const float* in;
  unsigned short* out;
  if (sub < nsub_x) { in = x; out = xq; }
  else { in = w; out = wq; sub -= nsub_x; }
  long base = (long)sub * 32 + (long)(gid & 7) * 4;
  const float4 v = *(const float4*)(in + base);
  float amax = fmaxf(fmaxf(fabsf(v.x), fabsf(v.y)), fmaxf(fabsf(v.z), fabsf(v.w)));
  amax = fmaxf(amax, __shfl_xor(amax, 1));
  amax = fmaxf(amax, __shfl_xor(amax, 2));
  amax = fmaxf(amax, __shfl_xor(amax, 4));
  const float bm = fmaxf(amax, 1e-12f);   // jnp.clip(max, 1e-12)
  const float scale = bm / 6.0f;

  const float T0 = bm * (0.25f / 6.0f);
  const float T1 = bm * (0.75f / 6.0f);
  const float T2 = bm * (1.25f / 6.0f);
  const float T3 = bm * (1.75f / 6.0f);
  const float T4 = bm * (2.5f  / 6.0f);
  const float T5 = bm * (3.5f  / 6.0f);
  const float T6 = bm * (5.0f  / 6.0f);

  float e[4] = {v.x, v.y, v.z, v.w};
  ushort4 o;
  unsigned short* op = (unsigned short*)&o;
#pragma unroll
  for (int i = 0; i < 4; i++) {
    float t = e[i];
    float a = fabsf(t);
    float p = 0.0f;
    p = (a > T0) ? 0.5f : p;
    p = (a > T1) ? 1.0f : p;
    p = (a > T2) ? 1.5f : p;
    p = (a > T3) ? 2.0f : p;
    p = (a > T4) ? 3.0f : p;
    p = (a > T5) ? 4.0f : p;
    p = (a > T6) ? 6.0f : p;
    op[i] = f2bf_bits(copysignf(p, t) * scale);
  }
  *(ushort4*)(out + base) = o;
}

#define MFMA(d, a, b) d = __builtin_amdgcn_mfma_f32_16x16x32_bf16(a, b, d, 0, 0, 0)

// LDS-free GEMM: C[M,N] = A[M,K] * B[N,K]^T, bf16 inputs, fp32 out.
// Each wave owns a 64x64 tile (4x4 grid of 16x16x32 MFMA); A/B fragments are
// loaded straight from global (L2-resident: A+B = 40 MB) as 16B/lane vector
// loads, double-buffered one K-step (32) ahead. No LDS, no __syncthreads.
// Block = 2x2 waves on a 128x128 tile so sibling waves share fragment lines in L1.
__global__ __launch_bounds__(256, 1) void gemm_direct(
    const unsigned short* __restrict__ A,  // [M, K]
    const unsigned short* __restrict__ B,  // [N, K]
    float* __restrict__ C, int M, int N) {
  const int tid = threadIdx.x;
  const int wave = tid >> 6;
  const int lane = tid & 63;
  const int wm = wave >> 1;
  const int wn = wave & 1;
  const int quad = lane >> 4;     // 0..3
  const int r16 = lane & 15;      // 0..15

  const int bm0 = blockIdx.y * 128 + wm * 64;
  const int bn0 = blockIdx.x * 128 + wn * 64;

  // Fragment base: lane reads A[m = bm0 + i*16 + r16][k + quad*8 .. +8]
  const unsigned short* Ab = A + (long)(bm0 + r16) * KDIM + quad * 8;
  const unsigned short* Bb = B + (long)(bn0 + r16) * KDIM + quad * 8;

  f32x4 acc[4][4] = {};
  bf16x8 a0[4], b0[4], a1[4], b1[4];

#pragma unroll
  for (int i = 0; i < 4; i++) {
    a0[i] = *(const bf16x8*)(Ab + (long)i * 16 * KDIM);
    b0[i] = *(const bf16x8*)(Bb + (long)i * 16 * KDIM);
  }

#pragma unroll 1
  for (int k = 0; k < KDIM - 64; k += 64) {
    // prefetch slice k+32
#pragma unroll
    for (int i = 0; i < 4; i++) {
      a1[i] = *(const bf16x8*)(Ab + (long)i * 16 * KDIM + k + 32);
      b1[i] = *(const bf16x8*)(Bb + (long)i * 16 * KDIM + k + 32);
    }
    // compute slice k
#pragma unroll
    for (int i = 0; i < 4; i++)
#pragma unroll
      for (int j = 0; j < 4; j++)
        MFMA(acc[i][j], a0[i], b0[j]);
    // prefetch slice k+64
#pragma unroll
    for (int i = 0; i < 4; i++) {
      a0[i] = *(const bf16x8*)(Ab + (long)i * 16 * KDIM + k + 64);
      b0[i] = *(const bf16x8*)(Bb + (long)i * 16 * KDIM + k + 64);
    }
    // compute slice k+32
#pragma unroll
    for (int i = 0; i < 4; i++)
#pragma unroll
      for (int j = 0; j < 4; j++)
        MFMA(acc[i][j], a1[i], b1[j]);
  }

  // Tail: a0 holds slice KDIM-64; load and compute final slice KDIM-32.
#pragma unroll
  for (int i = 0; i < 4; i++) {
    a1[i] = *(const bf16x8*)(Ab + (long)i * 16 * KDIM + KDIM - 32);
    b1[i] = *(const bf16x8*)(Bb + (long)i * 16 * KDIM + KDIM - 32);
  }
#pragma unroll
  for (int i = 0; i < 4; i++)
#pragma unroll
    for (int j = 0; j < 4; j++)
      MFMA(acc[i][j], a0[i], b0[j]);
#pragma unroll
  for (int i = 0; i < 4; i++)
#pragma unroll
    for (int j = 0; j < 4; j++)
      MFMA(acc[i][j], a1[i], b1[j]);

  // Epilogue: C/D layout col = lane&15, row = quad*4 + reg
#pragma unroll
  for (int i = 0; i < 4; i++) {
#pragma unroll
    for (int j = 0; j < 4; j++) {
      const int row = bm0 + i * 16 + quad * 4;
      const int col = bn0 + j * 16 + r16;
#pragma unroll
      for (int r = 0; r < 4; r++)
        C[(long)(row + r) * N + col] = acc[i][j][r];
    }
  }
}

extern "C" void kernel_launch(void* const* d_in, const int* in_sizes, int n_in,
                              void* d_out, int out_size, void* d_ws, size_t ws_size,
                              hipStream_t stream) {
  const float* x = (const float*)d_in[0];   // [M, K] fp32
  const float* w = (const float*)d_in[1];   // [N, K] fp32
  float* out = (float*)d_out;               // [M, N] fp32

  const int MK = in_sizes[0];
  const int NK = in_sizes[1];
  const int M = MK / KDIM;
  const int N = NK / KDIM;

  unsigned short* xq = (unsigned short*)d_ws;        // [M, K] bf16
  unsigned short* wq = xq + (size_t)MK;              // [N, K] bf16

  const int nsub_x = MK / 32;
  const int nsub_total = nsub_x + NK / 32;
  nvfp4_quant_dq2<<<dim3((nsub_total * 8 + 255) / 256), dim3(256), 0, stream>>>(
      x, xq, nsub_x, w, wq, nsub_total);

  dim3 grid(N / 128, M / 128);
  gemm_direct<<<grid, dim3(256), 0, stream>>>(xq, wq, out, M, N);
}

// Round 5
// 207.727 us; speedup vs baseline: 1.1805x; 1.1805x over previous
//
#include <hip/hip_runtime.h>
#include <hip/hip_bf16.h>
#include <stdint.h>

#define KDIM 4096
#define BM 256
#define BN 256
#define BK 32
#define KSPLIT 4
#define KCHUNK (KDIM / KSPLIT)   // 1024

typedef __attribute__((ext_vector_type(8))) short bf16x8;
typedef __attribute__((ext_vector_type(4))) float f32x4;

__device__ inline unsigned short f2bf_bits(float f) {
  union { __hip_bfloat16 h; unsigned short u; } cv;
  cv.h = __float2bfloat16(f);
  return cv.u;
}

// Fused quant+dequant for both tensors. One 8-lane subgroup = one 32-elem block.
// Palette selection via per-block thresholds (midpoint/6 * block_max);
// ties go to the LOWER palette value (argmin-first semantics).
__global__ void nvfp4_quant_dq2(const float* __restrict__ x, unsigned short* __restrict__ xq,
                                int nsub_x,
                                const float* __restrict__ w, unsigned short* __restrict__ wq,
                                int nsub_total) {
  int gid = blockIdx.x * blockDim.x + threadIdx.x;
  int sub = gid >> 3;
  if (sub >= nsub_total) return;
  const float* in;
  unsigned short* out;
  if (sub < nsub_x) { in = x; out = xq; }
  else { in = w; out = wq; sub -= nsub_x; }
  long base = (long)sub * 32 + (long)(gid & 7) * 4;
  const float4 v = *(const float4*)(in + base);
  float amax = fmaxf(fmaxf(fabsf(v.x), fabsf(v.y)), fmaxf(fabsf(v.z), fabsf(v.w)));
  amax = fmaxf(amax, __shfl_xor(amax, 1));
  amax = fmaxf(amax, __shfl_xor(amax, 2));
  amax = fmaxf(amax, __shfl_xor(amax, 4));
  const float bm = fmaxf(amax, 1e-12f);   // jnp.clip(max, 1e-12)
  const float scale = bm / 6.0f;

  const float T0 = bm * (0.25f / 6.0f);
  const float T1 = bm * (0.75f / 6.0f);
  const float T2 = bm * (1.25f / 6.0f);
  const float T3 = bm * (1.75f / 6.0f);
  const float T4 = bm * (2.5f  / 6.0f);
  const float T5 = bm * (3.5f  / 6.0f);
  const float T6 = bm * (5.0f  / 6.0f);

  float e[4] = {v.x, v.y, v.z, v.w};
  ushort4 o;
  unsigned short* op = (unsigned short*)&o;
#pragma unroll
  for (int i = 0; i < 4; i++) {
    float t = e[i];
    float a = fabsf(t);
    float p = 0.0f;
    p = (a > T0) ? 0.5f : p;
    p = (a > T1) ? 1.0f : p;
    p = (a > T2) ? 1.5f : p;
    p = (a > T3) ? 2.0f : p;
    p = (a > T4) ? 3.0f : p;
    p = (a > T5) ? 4.0f : p;
    p = (a > T6) ? 6.0f : p;
    op[i] = f2bf_bits(copysignf(p, t) * scale);
  }
  *(ushort4*)(out + base) = o;
}

#define MFMA(d, a, b) d = __builtin_amdgcn_mfma_f32_16x16x32_bf16(a, b, d, 0, 0, 0)

// C[M,N] += A[M,K](bf16) * B[N,K]^T(bf16), K-chunk blockIdx.z.
// 256x256 tile (halves staged volume vs 128x128: A re-read N/256=16x, B M/256=4x
// -> 256 MB of L2/L3 traffic total), split-K=4, grid (16,4,4)=256 blocks of
// 512 threads (8 waves, 2/SIMD). Wave tile 64x128 = 4x8 grid of 16x16x32 MFMA.
// Epilogue: fp32 atomicAdd into zeroed output.
__global__ __launch_bounds__(512, 2) void gemm_bt_256(
    const unsigned short* __restrict__ A,  // [M, K]
    const unsigned short* __restrict__ B,  // [N, K]
    float* __restrict__ C, int M, int N) {
  __shared__ unsigned short As[BM * BK];   // 16 KB
  __shared__ unsigned short Bs[BN * BK];   // 16 KB

  const int tid = threadIdx.x;
  const int wave = tid >> 6;      // 0..7
  const int lane = tid & 63;
  const int wm = wave >> 1;       // 0..3 (64-row strip)
  const int wn = wave & 1;        // 0..1 (128-col strip)
  const int quad = lane >> 4;     // 0..3
  const int r16 = lane & 15;      // 0..15

  const int bm0 = blockIdx.y * BM;
  const int bn0 = blockIdx.x * BN;
  const int kb = blockIdx.z * KCHUNK;

  // Staging: 32 chunks of 1 KB (16 rows x 32 k). Chunks 0..15 = A, 16..31 = B.
  // Each wave: 4 chunks = 4 x 16B global_load_lds per K-step.
  // Lane l covers row = chunk*16 + l/4, k = (l&3)*8; LDS dest = chunk*1024 + l*16 B.
  const int rstg = lane >> 2;          // 0..15
  const int kstg = (lane & 3) * 8;     // 0,8,16,24

  const unsigned short* gptr[4];
  unsigned short* lptr[4];
#pragma unroll
  for (int s = 0; s < 4; s++) {
    int cc = wave * 4 + s;
    if (cc < 16) {
      gptr[s] = A + (long)(bm0 + cc * 16 + rstg) * KDIM + kb + kstg;
      lptr[s] = As + cc * 512 + lane * 8;
    } else {
      int c2 = cc - 16;
      gptr[s] = B + (long)(bn0 + c2 * 16 + rstg) * KDIM + kb + kstg;
      lptr[s] = Bs + c2 * 512 + lane * 8;
    }
  }

  f32x4 acc[4][8] = {};

  for (int k0 = 0; k0 < KCHUNK; k0 += BK) {
#pragma unroll
    for (int s = 0; s < 4; s++) {
      __builtin_amdgcn_global_load_lds(
          (const __attribute__((address_space(1))) void*)gptr[s],
          (__attribute__((address_space(3))) void*)lptr[s], 16, 0, 0);
      gptr[s] += BK;
    }

    __syncthreads();

    bf16x8 af[4], bf[8];
#pragma unroll
    for (int i = 0; i < 4; i++) {
      const int arow = wm * 64 + i * 16 + r16;
      af[i] = *(const bf16x8*)(As + arow * BK + quad * 8);
    }
#pragma unroll
    for (int j = 0; j < 8; j++) {
      const int brow = wn * 128 + j * 16 + r16;
      bf[j] = *(const bf16x8*)(Bs + brow * BK + quad * 8);
    }

#pragma unroll
    for (int i = 0; i < 4; i++)
#pragma unroll
      for (int j = 0; j < 8; j++)
        MFMA(acc[i][j], af[i], bf[j]);

    __syncthreads();
  }

  // Epilogue: C/D layout col = lane&15, row = quad*4 + reg
#pragma unroll
  for (int i = 0; i < 4; i++) {
#pragma unroll
    for (int j = 0; j < 8; j++) {
      const int row = bm0 + wm * 64 + i * 16 + quad * 4;
      const int col = bn0 + wn * 128 + j * 16 + r16;
#pragma unroll
      for (int r = 0; r < 4; r++)
        atomicAdd(&C[(long)(row + r) * N + col], acc[i][j][r]);
    }
  }
}

extern "C" void kernel_launch(void* const* d_in, const int* in_sizes, int n_in,
                              void* d_out, int out_size, void* d_ws, size_t ws_size,
                              hipStream_t stream) {
  const float* x = (const float*)d_in[0];   // [M, K] fp32
  const float* w = (const float*)d_in[1];   // [N, K] fp32
  float* out = (float*)d_out;               // [M, N] fp32

  const int MK = in_sizes[0];
  const int NK = in_sizes[1];
  const int M = MK / KDIM;
  const int N = NK / KDIM;

  unsigned short* xq = (unsigned short*)d_ws;        // [M, K] bf16
  unsigned short* wq = xq + (size_t)MK;              // [N, K] bf16

  // Zero the output for the atomic split-K epilogue (graph-capturable).
  hipMemsetAsync(out, 0, (size_t)out_size * sizeof(float), stream);

  const int nsub_x = MK / 32;
  const int nsub_total = nsub_x + NK / 32;
  nvfp4_quant_dq2<<<dim3((nsub_total * 8 + 255) / 256), dim3(256), 0, stream>>>(
      x, xq, nsub_x, w, wq, nsub_total);

  dim3 grid(N / BN, M / BM, KSPLIT);
  gemm_bt_256<<<grid, dim3(512), 0, stream>>>(xq, wq, out, M, N);
}

// Round 6
// 176.941 us; speedup vs baseline: 1.3859x; 1.1740x over previous
//
#include <hip/hip_runtime.h>
#include <hip/hip_bf16.h>
#include <stdint.h>

#define KDIM 4096
#define BM 64
#define BN 128
#define KSPLIT 2
#define KCHUNK (KDIM / KSPLIT)   // 2048

typedef __attribute__((ext_vector_type(8))) short bf16x8;
typedef __attribute__((ext_vector_type(4))) float f32x4;

__device__ inline unsigned short f2bf_bits(float f) {
  union { __hip_bfloat16 h; unsigned short u; } cv;
  cv.h = __float2bfloat16(f);
  return cv.u;
}

// Fused quant+dequant for both tensors. One 8-lane subgroup = one 32-elem block.
// Palette selection via per-block thresholds (midpoint/6 * block_max);
// ties go to the LOWER palette value (argmin-first semantics).
__global__ void nvfp4_quant_dq2(const float* __restrict__ x, unsigned short* __restrict__ xq,
                                int nsub_x,
                                const float* __restrict__ w, unsigned short* __restrict__ wq,
                                int nsub_total) {
  int gid = blockIdx.x * blockDim.x + threadIdx.x;
  int sub = gid >> 3;
  if (sub >= nsub_total) return;
  const float* in;
  unsigned short* out;
  if (sub < nsub_x) { in = x; out = xq; }
  else { in = w; out = wq; sub -= nsub_x; }
  long base = (long)sub * 32 + (long)(gid & 7) * 4;
  const float4 v = *(const float4*)(in + base);
  float amax = fmaxf(fmaxf(fabsf(v.x), fabsf(v.y)), fmaxf(fabsf(v.z), fabsf(v.w)));
  amax = fmaxf(amax, __shfl_xor(amax, 1));
  amax = fmaxf(amax, __shfl_xor(amax, 2));
  amax = fmaxf(amax, __shfl_xor(amax, 4));
  const float bm = fmaxf(amax, 1e-12f);   // jnp.clip(max, 1e-12)
  const float scale = bm / 6.0f;

  const float T0 = bm * (0.25f / 6.0f);
  const float T1 = bm * (0.75f / 6.0f);
  const float T2 = bm * (1.25f / 6.0f);
  const float T3 = bm * (1.75f / 6.0f);
  const float T4 = bm * (2.5f  / 6.0f);
  const float T5 = bm * (3.5f  / 6.0f);
  const float T6 = bm * (5.0f  / 6.0f);

  float e[4] = {v.x, v.y, v.z, v.w};
  ushort4 o;
  unsigned short* op = (unsigned short*)&o;
#pragma unroll
  for (int i = 0; i < 4; i++) {
    float t = e[i];
    float a = fabsf(t);
    float p = 0.0f;
    p = (a > T0) ? 0.5f : p;
    p = (a > T1) ? 1.0f : p;
    p = (a > T2) ? 1.5f : p;
    p = (a > T3) ? 2.0f : p;
    p = (a > T4) ? 3.0f : p;
    p = (a > T5) ? 4.0f : p;
    p = (a > T6) ? 6.0f : p;
    op[i] = f2bf_bits(copysignf(p, t) * scale);
  }
  *(ushort4*)(out + base) = o;
}

#define MFMA(d, a, b) d = __builtin_amdgcn_mfma_f32_16x16x32_bf16(a, b, d, 0, 0, 0)
#define GLDS(g, l) __builtin_amdgcn_global_load_lds( \
    (const __attribute__((address_space(1))) void*)(g), \
    (__attribute__((address_space(3))) void*)(l), 16, 0, 0)

// C[M,N] += A[M,K] * B[N,K]^T over K-chunk blockIdx.z. 64x128 tile, TWO BK=32
// sub-tiles per barrier pair (16 MFMA/wave per drain), 4 waves (2x2), wave
// tile 32x64. Grid (32,16,2) = 1024 blocks -> 4 blocks/CU, 4 waves/SIMD.
// Epilogue: fp32 atomicAdd into zeroed output (2 partials -> deterministic).
__global__ __launch_bounds__(256, 4) void gemm_bt_dk(
    const unsigned short* __restrict__ A,  // [M, K]
    const unsigned short* __restrict__ B,  // [N, K]
    float* __restrict__ C, int M, int N) {
  __shared__ unsigned short As[2][BM * 32];   // 2 x 4 KB
  __shared__ unsigned short Bs[2][BN * 32];   // 2 x 8 KB

  const int tid = threadIdx.x;
  const int wave = tid >> 6;
  const int lane = tid & 63;
  const int wm = wave >> 1;       // 0..1  (32-row strip)
  const int wn = wave & 1;        // 0..1  (64-col strip)
  const int quad = lane >> 4;     // 0..3
  const int r16 = lane & 15;      // 0..15

  const int bm0 = blockIdx.y * BM;
  const int bn0 = blockIdx.x * BN;
  const int kb = blockIdx.z * KCHUNK;

  // Staging: 24 chunks of 1 KB (16 rows x 32 k) per 64-k iteration:
  //   idx 0..3  -> As[0] c0..3      idx 4..7  -> As[1] c0..3
  //   idx 8..15 -> Bs[0] c0..7      idx 16..23-> Bs[1] c0..7
  // Each wave stages 6 chunks. Lane covers row = c*16 + lane/4, k = (lane&3)*8.
  const int rstg = lane >> 2;          // 0..15
  const int kstg = (lane & 3) * 8;     // 0,8,16,24

  const unsigned short* gptr[6];
  unsigned short* lptr[6];
#pragma unroll
  for (int s = 0; s < 6; s++) {
    int idx = wave * 6 + s;
    int t, c;       // tile (0/1 = k-offset 0/32), chunk row-group
    const unsigned short* src;
    unsigned short* dst;
    if (idx < 8) {            // A chunks
      t = idx >> 2; c = idx & 3;
      src = A + (long)(bm0 + c * 16 + rstg) * KDIM + kb + t * 32 + kstg;
      dst = As[t] + c * 512 + lane * 8;
    } else {                  // B chunks
      int bidx = idx - 8;
      t = bidx >> 3; c = bidx & 7;
      src = B + (long)(bn0 + c * 16 + rstg) * KDIM + kb + t * 32 + kstg;
      dst = Bs[t] + c * 512 + lane * 8;
    }
    gptr[s] = src;
    lptr[s] = dst;
  }

  f32x4 acc[2][4] = {};

  for (int k0 = 0; k0 < KCHUNK; k0 += 64) {
#pragma unroll
    for (int s = 0; s < 6; s++) {
      GLDS(gptr[s], lptr[s]);
      gptr[s] += 64;
    }

    __syncthreads();

    bf16x8 af[2][2], bf[2][4];
#pragma unroll
    for (int t = 0; t < 2; t++) {
#pragma unroll
      for (int i = 0; i < 2; i++)
        af[t][i] = *(const bf16x8*)(As[t] + (wm * 32 + i * 16 + r16) * 32 + quad * 8);
#pragma unroll
      for (int j = 0; j < 4; j++)
        bf[t][j] = *(const bf16x8*)(Bs[t] + (wn * 64 + j * 16 + r16) * 32 + quad * 8);
    }

#pragma unroll
    for (int t = 0; t < 2; t++)
#pragma unroll
      for (int i = 0; i < 2; i++)
#pragma unroll
        for (int j = 0; j < 4; j++)
          MFMA(acc[i][j], af[t][i], bf[t][j]);

    __syncthreads();
  }

  // Epilogue: C/D layout col = lane&15, row = quad*4 + reg
#pragma unroll
  for (int i = 0; i < 2; i++) {
#pragma unroll
    for (int j = 0; j < 4; j++) {
      const int row = bm0 + wm * 32 + i * 16 + quad * 4;
      const int col = bn0 + wn * 64 + j * 16 + r16;
#pragma unroll
      for (int r = 0; r < 4; r++)
        atomicAdd(&C[(long)(row + r) * N + col], acc[i][j][r]);
    }
  }
}

extern "C" void kernel_launch(void* const* d_in, const int* in_sizes, int n_in,
                              void* d_out, int out_size, void* d_ws, size_t ws_size,
                              hipStream_t stream) {
  const float* x = (const float*)d_in[0];   // [M, K] fp32
  const float* w = (const float*)d_in[1];   // [N, K] fp32
  float* out = (float*)d_out;               // [M, N] fp32

  const int MK = in_sizes[0];
  const int NK = in_sizes[1];
  const int M = MK / KDIM;
  const int N = NK / KDIM;

  unsigned short* xq = (unsigned short*)d_ws;        // [M, K] bf16
  unsigned short* wq = xq + (size_t)MK;              // [N, K] bf16

  // Zero the output for the atomic split-K epilogue (graph-capturable).
  hipMemsetAsync(out, 0, (size_t)out_size * sizeof(float), stream);

  const int nsub_x = MK / 32;
  const int nsub_total = nsub_x + NK / 32;
  nvfp4_quant_dq2<<<dim3((nsub_total * 8 + 255) / 256), dim3(256), 0, stream>>>(
      x, xq, nsub_x, w, wq, nsub_total);

  dim3 grid(N / BN, M / BM, KSPLIT);
  gemm_bt_dk<<<grid, dim3(256), 0, stream>>>(xq, wq, out, M, N);
}